// Round 1
// baseline (1993.973 us; speedup 1.0000x reference)
//
#include <hip/hip_runtime.h>

#define BLOCK 256
#define GG 8            // nodes per block; 100000 % 8 == 0 -> 12500 blocks
#define ROWS 48         // 6 * GG  (per node: 1 h0 row + 5 h1 rows)
#define ATS 52          // AT row stride (floats): 16B-aligned (52*4=208), not 0 mod 32 banks
#define SMEM_FLOATS 14336  // max(256*ATS=13312, 48*256 + 256*8 = 14336)

__device__ __forceinline__ float sigm(float x) { return 1.0f / (1.0f + __expf(-x)); }

// Pack weights into K-major (transposed) layout in workspace:
//  W1T[256][256]: k<128 -> x_self part, k>=128 -> neigh part; j<128 sigmoid (Wl1/Wr1), j>=128 spike (Wlt1/Wrt1)
//  W2T[256][128]: k<128 -> h0p part,   k>=128 -> neigh2 part; j<64 sigmoid (Wl2/Wr2),  j>=64  spike (Wlt2/Wrt2)
__global__ void pack_weights_k(const float* __restrict__ Wl1, const float* __restrict__ Wr1,
                               const float* __restrict__ Wlt1, const float* __restrict__ Wrt1,
                               const float* __restrict__ Wl2, const float* __restrict__ Wr2,
                               const float* __restrict__ Wlt2, const float* __restrict__ Wrt2,
                               float* __restrict__ W1T, float* __restrict__ W2T) {
  int idx = blockIdx.x * BLOCK + threadIdx.x;
  if (idx < 256 * 256) {
    int k = idx >> 8, j = idx & 255;
    int jj = j & 127, kk = k & 127;
    const float* src = (j < 128) ? ((k < 128) ? Wl1 : Wr1)
                                 : ((k < 128) ? Wlt1 : Wrt1);
    W1T[idx] = src[jj * 128 + kk];
  } else {
    int i2 = idx - 256 * 256;
    if (i2 < 256 * 128) {
      int k = i2 >> 7, j = i2 & 127;
      int jj = j & 63, kk = k & 127;
      const float* src = (j < 64) ? ((k < 128) ? Wl2 : Wr2)
                                  : ((k < 128) ? Wlt2 : Wrt2);
      W2T[i2] = src[jj * 128 + kk];
    }
  }
}

__global__ __launch_bounds__(BLOCK)
void signn_fused_k(const float* __restrict__ h0, const float* __restrict__ h1,
                   const float* __restrict__ h2, const float* __restrict__ W1T,
                   const float* __restrict__ W2T, float* __restrict__ out) {
  __shared__ float sm[SMEM_FLOATS];
  float* AT  = sm;               // [256][ATS]  A^T: k-major, m = 0..47
  float* scr = sm;               // [48][256]   layer-1 pre-acts, then out_s (phase 2)
  float* A2T = sm + ROWS * 256;  // [256][8]    layer-2 A^T

  const int tid = threadIdx.x;
  const int n0 = blockIdx.x * GG;

  // ---------------- stage A^T: 48 rows x (128 x_self | 128 neigh) ----------------
  for (int it = tid; it < ROWS * 32; it += BLOCK) {
    const int m = it >> 5, ch = it & 31;        // ch: float4 chunk of 128-d feature
    const int g = m / 6, r = m - 6 * g;
    const int n = n0 + g;
    float4 xs, ng;
    if (r == 0) {
      xs = *(const float4*)(h0 + n * 128 + ch * 4);
      const float* b = h1 + (n * 5) * 128 + ch * 4;
      const float4 s0 = *(const float4*)(b);
      const float4 s1 = *(const float4*)(b + 128);
      const float4 s2 = *(const float4*)(b + 256);
      const float4 s3 = *(const float4*)(b + 384);
      const float4 s4 = *(const float4*)(b + 512);
      ng.x = (s0.x + s1.x + s2.x + s3.x + s4.x) * 0.2f;
      ng.y = (s0.y + s1.y + s2.y + s3.y + s4.y) * 0.2f;
      ng.z = (s0.z + s1.z + s2.z + s3.z + s4.z) * 0.2f;
      ng.w = (s0.w + s1.w + s2.w + s3.w + s4.w) * 0.2f;
    } else {
      const int i = n * 5 + (r - 1);
      xs = *(const float4*)(h1 + i * 128 + ch * 4);
      const float4 a  = *(const float4*)(h2 + (2 * i) * 128 + ch * 4);
      const float4 b2 = *(const float4*)(h2 + (2 * i + 1) * 128 + ch * 4);
      ng.x = (a.x + b2.x) * 0.5f;
      ng.y = (a.y + b2.y) * 0.5f;
      ng.z = (a.z + b2.z) * 0.5f;
      ng.w = (a.w + b2.w) * 0.5f;
    }
    const int k0 = ch * 4;
    AT[(k0 + 0) * ATS + m] = xs.x;
    AT[(k0 + 1) * ATS + m] = xs.y;
    AT[(k0 + 2) * ATS + m] = xs.z;
    AT[(k0 + 3) * ATS + m] = xs.w;
    AT[(128 + k0 + 0) * ATS + m] = ng.x;
    AT[(128 + k0 + 1) * ATS + m] = ng.y;
    AT[(128 + k0 + 2) * ATS + m] = ng.z;
    AT[(128 + k0 + 3) * ATS + m] = ng.w;
  }
  __syncthreads();

  // ---------------- layer-1 GEMM: M=48, N=256 (128 sig | 128 spk), K=256 ----------------
  const int tj = tid & 63;   // col group: cols 4*tj .. 4*tj+3 (covers all 256 per wave)
  const int tm = tid >> 6;   // row group: rows 12*tm .. 12*tm+11 (one group per wave)
  const int m0 = tm * 12;

  float acc[12][4];
  #pragma unroll
  for (int mm = 0; mm < 12; ++mm) {
    acc[mm][0] = 0.f; acc[mm][1] = 0.f; acc[mm][2] = 0.f; acc[mm][3] = 0.f;
  }

  const float* wp = W1T + tj * 4;
  #pragma unroll 2
  for (int k = 0; k < 256; ++k) {
    const float4 w = *(const float4*)(wp + (k << 8));   // coalesced, L2-resident
    const float* ap = AT + k * ATS + m0;                 // wave-uniform -> LDS broadcast
    const float4 a0 = *(const float4*)(ap);
    const float4 a1 = *(const float4*)(ap + 4);
    const float4 a2 = *(const float4*)(ap + 8);
    const float av[12] = {a0.x, a0.y, a0.z, a0.w, a1.x, a1.y, a1.z, a1.w,
                          a2.x, a2.y, a2.z, a2.w};
    #pragma unroll
    for (int mm = 0; mm < 12; ++mm) {
      acc[mm][0] = fmaf(av[mm], w.x, acc[mm][0]);
      acc[mm][1] = fmaf(av[mm], w.y, acc[mm][1]);
      acc[mm][2] = fmaf(av[mm], w.z, acc[mm][2]);
      acc[mm][3] = fmaf(av[mm], w.w, acc[mm][3]);
    }
  }
  __syncthreads();  // everyone done reading AT before scr overwrites it

  #pragma unroll
  for (int mm = 0; mm < 12; ++mm) {
    float4 v;
    v.x = acc[mm][0]; v.y = acc[mm][1]; v.z = acc[mm][2]; v.w = acc[mm][3];
    *(float4*)(scr + (m0 + mm) * 256 + tj * 4) = v;
  }
  __syncthreads();

  // ---------------- out_s = sigmoid(x) * spike(t), in place ----------------
  for (int it = tid; it < ROWS * 128; it += BLOCK) {
    const int m = it >> 7, j = it & 127;
    const float x = scr[m * 256 + j];
    const float t = scr[m * 256 + 128 + j];
    scr[m * 256 + j] = sigm(x) * (t >= 1.0f ? 1.0f : 0.0f);
  }
  __syncthreads();

  // ---------------- build A2^T: [256][8]  (h0p | neigh2) ----------------
  for (int it = tid; it < 256 * GG; it += BLOCK) {
    const int g = it >> 8, k2 = it & 255;
    float v;
    if (k2 < 128) {
      v = scr[(g * 6) * 256 + k2];
    } else {
      const int c = k2 - 128;
      v = (scr[(g * 6 + 1) * 256 + c] + scr[(g * 6 + 2) * 256 + c] +
           scr[(g * 6 + 3) * 256 + c] + scr[(g * 6 + 4) * 256 + c] +
           scr[(g * 6 + 5) * 256 + c]) * 0.2f;
    }
    A2T[k2 * 8 + g] = v;
  }
  __syncthreads();

  // ---------------- layer-2 GEMM: M=8, N=128 (64 sig | 64 spk), K=256 ----------------
  const int j2 = tid & 127;
  const int gh = tid >> 7;   // 0/1 -> rows gh*4..gh*4+3
  float a2[4] = {0.f, 0.f, 0.f, 0.f};
  #pragma unroll 4
  for (int k = 0; k < 256; ++k) {
    const float w = W2T[(k << 7) + j2];                    // coalesced
    const float4 av = *(const float4*)(A2T + k * 8 + gh * 4);  // broadcast
    a2[0] = fmaf(av.x, w, a2[0]);
    a2[1] = fmaf(av.y, w, a2[1]);
    a2[2] = fmaf(av.z, w, a2[2]);
    a2[3] = fmaf(av.w, w, a2[3]);
  }
  // scr rows 0..3 region ([0..1024)) is dead now (A2T-build barrier passed); reuse as scr2[8][128]
  #pragma unroll
  for (int q = 0; q < 4; ++q) scr[(gh * 4 + q) * 128 + j2] = a2[q];
  __syncthreads();

  // ---------------- epilogue: out = sigmoid(x2) * spike(t2) ----------------
  for (int it = tid; it < GG * 64; it += BLOCK) {
    const int g = it >> 6, j = it & 63;
    const float x = scr[g * 128 + j];
    const float t = scr[g * 128 + 64 + j];
    out[(n0 + g) * 64 + j] = sigm(x) * (t >= 1.0f ? 1.0f : 0.0f);
  }
}

extern "C" void kernel_launch(void* const* d_in, const int* in_sizes, int n_in,
                              void* d_out, int out_size, void* d_ws, size_t ws_size,
                              hipStream_t stream) {
  const float* h0 = (const float*)d_in[0];
  const float* h1 = (const float*)d_in[1];
  const float* h2 = (const float*)d_in[2];
  float* W1T = (float*)d_ws;             // 256*256 floats
  float* W2T = W1T + 256 * 256;          // 256*128 floats (total 384 KB of d_ws)

  const int pack_items = 256 * 256 + 256 * 128;
  pack_weights_k<<<(pack_items + BLOCK - 1) / BLOCK, BLOCK, 0, stream>>>(
      (const float*)d_in[3], (const float*)d_in[4], (const float*)d_in[5],
      (const float*)d_in[6], (const float*)d_in[7], (const float*)d_in[8],
      (const float*)d_in[9], (const float*)d_in[10], W1T, W2T);

  signn_fused_k<<<100000 / GG, BLOCK, 0, stream>>>(h0, h1, h2, W1T, W2T,
                                                   (float*)d_out);
}